// Round 1
// baseline (204.441 us; speedup 1.0000x reference)
//
#include <hip/hip_runtime.h>

// Problem constants (B,T,U) = (32,1024,1024) from the reference.
#define BB 32
#define TT 1024
#define UU 1024
#define CHUNKS 16
#define LCH (TT / CHUNKS)   // 64 timesteps per chunk

__device__ __forceinline__ float fast_rcp(float x) {
    return __builtin_amdgcn_rcpf(x);
}
__device__ __forceinline__ float sigmoid_f(float x) {
    // 1/(1+e^-x); v_exp_f32 + v_rcp_f32
    return fast_rcp(1.0f + __expf(-x));
}
__device__ __forceinline__ float tanh_f(float x) {
    // tanh(x) = 1 - 2/(e^{2x}+1); saturates correctly at +/-1 for large |x|
    return 1.0f - 2.0f * fast_rcp(1.0f + __expf(2.0f * x));
}

// Kernel 1: per-(b,u,chunk) affine-map reduction over LCH timesteps.
// idx = chunk*B*U + b*U + u  -> consecutive lanes read consecutive u (coalesced).
__global__ __launch_bounds__(256) void lstm_chunk_kernel(
    const float* __restrict__ x,        // [B,T,U]
    const float* __restrict__ w_gates,  // [4U]
    const float* __restrict__ b_gates,  // [4U]
    float2* __restrict__ fp)            // [CHUNKS, B, U] (F, P)
{
    const int idx   = blockIdx.x * 256 + threadIdx.x;
    const int u     = idx & (UU - 1);
    const int b     = (idx >> 10) & (BB - 1);
    const int chunk = idx >> 15;   // idx / (B*U)

    const float wi = w_gates[u];
    const float wf = w_gates[UU + u];
    const float wg = w_gates[2 * UU + u];
    const float bi = b_gates[u];
    const float bf = b_gates[UU + u];
    const float bg = b_gates[2 * UU + u];

    const float* xp = x + ((size_t)b * TT + (size_t)chunk * LCH) * UU + u;

    float F = 1.0f;   // running product of f
    float P = 0.0f;   // running affine offset
#pragma unroll 8
    for (int j = 0; j < LCH; ++j) {
        const float xv = xp[(size_t)j * UU];
        const float ig = sigmoid_f(fmaf(wi, xv, bi));
        const float fg = sigmoid_f(fmaf(wf, xv, bf));
        const float gg = tanh_f(fmaf(wg, xv, bg));
        P = fmaf(fg, P, ig * gg);
        F *= fg;
    }
    fp[idx] = make_float2(F, P);
}

// Kernel 2: fold chunk affine maps, final gate, dense reduction per batch.
__global__ __launch_bounds__(256) void lstm_final_kernel(
    const float2* __restrict__ fp,      // [CHUNKS, B, U]
    const float* __restrict__ x,        // [B,T,U]
    const float* __restrict__ w_gates,
    const float* __restrict__ b_gates,
    const float* __restrict__ w_dense,  // [U]
    const float* __restrict__ b_dense,  // [1]
    float* __restrict__ out)            // [B]
{
    const int b   = blockIdx.x;
    const int tid = threadIdx.x;

    float sum = 0.0f;
#pragma unroll
    for (int k = 0; k < UU / 256; ++k) {
        const int u = tid + k * 256;
        float c = 0.0f;
#pragma unroll
        for (int ch = 0; ch < CHUNKS; ++ch) {
            const float2 v = fp[(size_t)ch * BB * UU + (size_t)b * UU + u];
            c = fmaf(v.x, c, v.y);
        }
        const float xv = x[((size_t)b * TT + (TT - 1)) * UU + u];
        const float o  = sigmoid_f(fmaf(w_gates[3 * UU + u], xv, b_gates[3 * UU + u]));
        const float h  = o * tanh_f(c);
        sum += h * w_dense[u];
    }

    __shared__ float red[256];
    red[tid] = sum;
    __syncthreads();
#pragma unroll
    for (int s = 128; s > 0; s >>= 1) {
        if (tid < s) red[tid] += red[tid + s];
        __syncthreads();
    }
    if (tid == 0) out[b] = red[0] + b_dense[0];
}

extern "C" void kernel_launch(void* const* d_in, const int* in_sizes, int n_in,
                              void* d_out, int out_size, void* d_ws, size_t ws_size,
                              hipStream_t stream) {
    const float* x       = (const float*)d_in[0];
    const float* w_gates = (const float*)d_in[1];
    const float* b_gates = (const float*)d_in[2];
    const float* w_dense = (const float*)d_in[3];
    const float* b_dense = (const float*)d_in[4];
    float* out = (float*)d_out;
    float2* fp = (float2*)d_ws;   // needs CHUNKS*B*U*8 = 4 MB of workspace

    const int total = BB * UU * CHUNKS;           // 524288 threads
    lstm_chunk_kernel<<<total / 256, 256, 0, stream>>>(x, w_gates, b_gates, fp);
    lstm_final_kernel<<<BB, 256, 0, stream>>>(fp, x, w_gates, b_gates,
                                              w_dense, b_dense, out);
}